// Round 7
// baseline (6423.491 us; speedup 1.0000x reference)
//
#include <hip/hip_runtime.h>
#include <stdint.h>

#define BM 128
#define BN 128
#define BK 64

// s_waitcnt simm16 (gfx9/CDNA): vm[3:0] | exp[6:4]<<4 | lgkm[11:8]<<8 | vm_hi[5:4]<<14
#define WAIT_LGKM0 0xC07F   // lgkmcnt(0), vmcnt/expcnt = no-wait

typedef __bf16 bf16x8 __attribute__((ext_vector_type(8)));
typedef float f32x4 __attribute__((ext_vector_type(4)));

__device__ __forceinline__ float bf2f(uint16_t u) {
  union { uint32_t u32; float f; } x; x.u32 = ((uint32_t)u) << 16; return x.f;
}
// round-to-nearest-even f32 -> bf16 (finite values only)
__device__ __forceinline__ uint16_t f2bf(float f) {
  uint32_t x = __float_as_uint(f);
  uint32_t r = (x + 0x7FFFu + ((x >> 16) & 1u)) >> 16;
  return (uint16_t)r;
}

// --- pipeline helpers -------------------------------------------------------
__device__ __forceinline__ void stage_regs(const uint16_t* ga, const uint16_t* gb,
                                           int ldA, int ldB,
                                           uint4 a[4], uint4 b[4]) {
#pragma unroll
  for (int c = 0; c < 4; ++c) {
    a[c] = *(const uint4*)(ga + (size_t)(c * 32) * ldA);
    b[c] = *(const uint4*)(gb + (size_t)(c * 32) * ldB);
  }
}
__device__ __forceinline__ void write_lds(uint16_t* la, uint16_t* lb,
                                          const uint4 a[4], const uint4 b[4]) {
#pragma unroll
  for (int c = 0; c < 4; ++c) {
    *(uint4*)(la + c * 2048) = a[c];
    *(uint4*)(lb + c * 2048) = b[c];
  }
}
__device__ __forceinline__ void mfma_phase(const uint16_t* ldsA, const uint16_t* ldsB,
                                           int ln, int wr, int wc, f32x4 acc[4][4]) {
#pragma unroll
  for (int kk = 0; kk < 2; ++kk) {
    const int kc = (kk << 2) + (ln >> 4);   // logical 16B chunk in K
    const int sw = (kc ^ (ln & 7)) << 3;    // XOR-swizzled elem offset
    bf16x8 af[4], bfr[4];
#pragma unroll
    for (int mt = 0; mt < 4; ++mt)
      af[mt] = *(const bf16x8*)&ldsA[((wr << 6) + (mt << 4) + (ln & 15)) * BK + sw];
#pragma unroll
    for (int nt = 0; nt < 4; ++nt)
      bfr[nt] = *(const bf16x8*)&ldsB[((wc << 6) + (nt << 4) + (ln & 15)) * BK + sw];
#pragma unroll
    for (int mt = 0; mt < 4; ++mt)
#pragma unroll
      for (int nt = 0; nt < 4; ++nt)
        acc[mt][nt] = __builtin_amdgcn_mfma_f32_16x16x32_bf16(
            af[mt], bfr[nt], acc[mt][nt], 0, 0, 0);
  }
}

// C(BMxBN at m0,n0) += A(MxK row-major bf16) * Bt(NxK row-major bf16)^T
// REGISTER-PIPELINED K-loop, single 32 KB LDS buffer pair:
//   [regs hold tile k] barrier(readers done) -> ds_write tile k (compiler's
//   auto vmcnt wait for these regs lands HERE — one full compute phase after
//   the loads were issued) -> issue global_load tile k+1 -> regs ->
//   waitcnt lgkm(0) -> barrier(data ready) -> compute tile k.
// No global_load_lds: rounds 5/6 showed the compiler full-drains vmcnt before
// ds_read when LDS-writing vmem ops are in flight (can't disprove aliasing).
// VGPR-mediated staging makes every dependence explicit through registers.
// XOR swizzle (round 4): global chunk gc=(t&7)^(row&7) -> LDS slot (t&7);
// frag reads spread over all 32 banks. K-order/MFMA order unchanged ->
// bit-identical numerics (absmax must stay 0.01953125).
__device__ __forceinline__ void gemm_tile(
    const uint16_t* __restrict__ A, int ldA,
    const uint16_t* __restrict__ Bt, int ldB,
    int m0, int n0, int K,
    uint16_t* ldsA, uint16_t* ldsB, f32x4 acc[4][4])
{
  const int t  = threadIdx.x;
  const int ln = t & 63;
  const int wv = t >> 6;
  const int wr = wv >> 1, wc = wv & 1;

  const int row = t >> 3;
  const int gc  = (t & 7) ^ (row & 7);
  const uint16_t* ga = A  + (size_t)(m0 + row) * ldA + (gc << 3);
  const uint16_t* gb = Bt + (size_t)(n0 + row) * ldB + (gc << 3);
  uint16_t* la = ldsA + (t << 3);
  uint16_t* lb = ldsB + (t << 3);

  const int nIter = K >> 6;        // 16 or 32 (always even)
  uint4 ra[4], rb[4], pa[4], pb[4];

  stage_regs(ga, gb, ldA, ldB, ra, rb);  ga += BK; gb += BK;

  for (int kp = 0; kp < (nIter >> 1); ++kp) {
    const int kt = kp << 1;
    // ---- even iter: consume ra/rb, prefetch pa/pb (always valid: kt+1<nIter)
    __builtin_amdgcn_s_barrier();                   // readers of prev tile done
    write_lds(la, lb, ra, rb);                      // auto vmcnt wait (old loads)
    stage_regs(ga, gb, ldA, ldB, pa, pb);  ga += BK; gb += BK;
    __builtin_amdgcn_s_waitcnt(WAIT_LGKM0);         // my ds_writes done
    __builtin_amdgcn_s_barrier();                   // tile visible to all waves
    mfma_phase(ldsA, ldsB, ln, wr, wc, acc);
    // ---- odd iter: consume pa/pb, prefetch ra/rb if a next pair exists
    __builtin_amdgcn_s_barrier();
    write_lds(la, lb, pa, pb);
    if (kt + 2 < nIter) { stage_regs(ga, gb, ldA, ldB, ra, rb); ga += BK; gb += BK; }
    __builtin_amdgcn_s_waitcnt(WAIT_LGKM0);
    __builtin_amdgcn_s_barrier();
    mfma_phase(ldsA, ldsB, ln, wr, wc, acc);
  }
}

// One Jacobi relaxation step, 3 GEMMs fused in one 640-block grid.
// LPT order (long blocks first) + XCD-aware map: XCD x owns bm in {2x,2x+1}.
//  b <256 (mode 1): pre1 = s2 @ W1^T + s0 @ W0   (K=2048 pass + K=1024 pass)
//  b <512 (mode 2): pre2 = s1 @ W1               (Bt = W1Tb)
//  else   (mode 0): pre0 = s1 @ W0^T             (Bt = W0b native)
// fp32 masters (in d_out) updated in place; bf16 shadows double-buffered.
__global__ void step_kernel(
    const uint16_t* __restrict__ s0b_c, const uint16_t* __restrict__ s1b_c,
    const uint16_t* __restrict__ s2b_c,
    uint16_t* __restrict__ s0b_n, uint16_t* __restrict__ s1b_n,
    uint16_t* __restrict__ s2b_n,
    const uint16_t* __restrict__ W0b, const uint16_t* __restrict__ W0Tb,
    const uint16_t* __restrict__ W1b, const uint16_t* __restrict__ W1Tb,
    const float* __restrict__ b0, const float* __restrict__ b1,
    const float* __restrict__ c2f,
    float* __restrict__ s0f, float* __restrict__ s1f, float* __restrict__ s2f)
{
  __shared__ uint16_t ldsA[BM * BK];
  __shared__ uint16_t ldsB[BN * BK];

  f32x4 acc[4][4];
  const f32x4 z = {0.f, 0.f, 0.f, 0.f};
#pragma unroll
  for (int i = 0; i < 4; ++i)
#pragma unroll
    for (int j = 0; j < 4; ++j) acc[i][j] = z;

  const int b = blockIdx.x;
  int mode, bm, bn;
  if (b < 256) {
    mode = 1; const int x = b & 7, j = b >> 3;           // j in [0,32)
    bm = (x << 1) + (j >> 4); bn = j & 15;
    gemm_tile(s2b_c, 2048, W1b, 2048, bm * BM, bn * BN, 2048, ldsA, ldsB, acc);
    gemm_tile(s0b_c, 1024, W0Tb, 1024, bm * BM, bn * BN, 1024, ldsA, ldsB, acc);
  } else if (b < 512) {
    mode = 2; const int u = b - 256, x = u & 7, j = u >> 3;
    bm = (x << 1) + (j >> 4); bn = j & 15;
    gemm_tile(s1b_c, 2048, W1Tb, 2048, bm * BM, bn * BN, 2048, ldsA, ldsB, acc);
  } else {
    mode = 0; const int u = b - 512, x = u & 7, j = u >> 3; // j in [0,16)
    bm = (x << 1) + (j >> 3); bn = j & 7;
    gemm_tile(s1b_c, 2048, W0b, 2048, bm * BM, bn * BN, 2048, ldsA, ldsB, acc);
  }

  const int t = threadIdx.x, wv = t >> 6, ln = t & 63;
  const int wr = wv >> 1, wc = wv & 1;
  const int rb = (ln >> 4) << 2, cc = ln & 15;
  const int m0 = bm * BM, n0 = bn * BN;

#pragma unroll
  for (int mt = 0; mt < 4; ++mt) {
#pragma unroll
    for (int nt = 0; nt < 4; ++nt) {
      const int gn = n0 + (wc << 6) + (nt << 4) + cc;
      float add = 0.f;
      if (mode == 0) add = b0[gn];
      else if (mode == 1) add = b1[gn];
#pragma unroll
      for (int r = 0; r < 4; ++r) {
        const int gm = m0 + (wr << 6) + (mt << 4) + rb + r;
        const float pre = acc[mt][nt][r];
        if (mode == 0) {
          const size_t ix = (size_t)gm * 1024 + gn;
          float nv = 0.8f * s0f[ix] + 0.2f * (pre + add);
          nv = fminf(fmaxf(nv, 0.f), 1.f);
          s0f[ix] = nv;
          s0b_n[ix] = f2bf(nv);
        } else if (mode == 1) {
          const size_t ix = (size_t)gm * 2048 + gn;
          float nv = 0.8f * s1f[ix] + 0.2f * (pre + add);
          nv = fminf(fmaxf(nv, 0.f), 1.f);
          s1f[ix] = nv;
          s1b_n[ix] = f2bf(nv);
        } else {
          const size_t ix = (size_t)gm * 2048 + gn;
          float nv = 0.8f * s2f[ix] + 0.2f * (pre + c2f[ix]);
          nv = fminf(fmaxf(nv, 0.f), 1.f);
          s2f[ix] = nv;
          s2b_n[ix] = f2bf(nv);
        }
      }
    }
  }
}

// c2 = data @ W2^T + b2 (step-invariant), fp32 result.
__global__ void c2_kernel(const uint16_t* __restrict__ datab,
                          const uint16_t* __restrict__ W2b,
                          const float* __restrict__ b2,
                          float* __restrict__ c2f)
{
  __shared__ uint16_t ldsA[BM * BK];
  __shared__ uint16_t ldsB[BN * BK];
  f32x4 acc[4][4];
  const f32x4 z = {0.f, 0.f, 0.f, 0.f};
#pragma unroll
  for (int i = 0; i < 4; ++i)
#pragma unroll
    for (int j = 0; j < 4; ++j) acc[i][j] = z;

  const int bm = blockIdx.x >> 4, bn = blockIdx.x & 15;
  gemm_tile(datab, 2048, W2b, 2048, bm * BM, bn * BN, 2048, ldsA, ldsB, acc);

  const int t = threadIdx.x, wv = t >> 6, ln = t & 63;
  const int wr = wv >> 1, wc = wv & 1;
  const int rb = (ln >> 4) << 2, cc = ln & 15;
  const int m0 = bm * BM, n0 = bn * BN;
#pragma unroll
  for (int mt = 0; mt < 4; ++mt)
#pragma unroll
    for (int nt = 0; nt < 4; ++nt) {
      const int gn = n0 + (wc << 6) + (nt << 4) + cc;
      const float bb = b2[gn];
#pragma unroll
      for (int r = 0; r < 4; ++r) {
        const int gm = m0 + (wr << 6) + (mt << 4) + rb + r;
        c2f[(size_t)gm * 2048 + gn] = acc[mt][nt][r] + bb;
      }
    }
}

// fp32 -> bf16 straight convert, 4 elems/thread.
__global__ void conv_k(const float* __restrict__ src, uint16_t* __restrict__ dst)
{
  const size_t i4 = ((size_t)blockIdx.x * 256 + threadIdx.x) << 2;
  const float4 v = *(const float4*)(src + i4);
  ushort4 o;
  o.x = f2bf(v.x); o.y = f2bf(v.y); o.z = f2bf(v.z); o.w = f2bf(v.w);
  *(ushort4*)(dst + i4) = o;
}

// fp32 -> bf16 transposed: dst[c*ldD + r] = bf16(src[r*ldS + c]).
__global__ void convT_k(const float* __restrict__ src, uint16_t* __restrict__ dst,
                        int ldS, int ldD)
{
  __shared__ uint16_t tile[32][33];
  const int r0 = blockIdx.y * 32, c0 = blockIdx.x * 32;
  tile[threadIdx.y][threadIdx.x] =
      f2bf(src[(size_t)(r0 + threadIdx.y) * ldS + c0 + threadIdx.x]);
  __syncthreads();
  dst[(size_t)(c0 + threadIdx.y) * ldD + r0 + threadIdx.x] = tile[threadIdx.x][threadIdx.y];
}

// fp32 input -> fp32 master (in d_out) + bf16 shadow. 4 elems/thread.
__global__ void init_state(const float* __restrict__ in,
                           float* __restrict__ sf, uint16_t* __restrict__ sb)
{
  const size_t i4 = ((size_t)blockIdx.x * 256 + threadIdx.x) << 2;
  const float4 v = *(const float4*)(in + i4);
  *(float4*)(sf + i4) = v;
  ushort4 o;
  o.x = f2bf(v.x); o.y = f2bf(v.y); o.z = f2bf(v.z); o.w = f2bf(v.w);
  *(ushort4*)(sb + i4) = o;
}

extern "C" void kernel_launch(void* const* d_in, const int* in_sizes, int n_in,
                              void* d_out, int out_size, void* d_ws, size_t ws_size,
                              hipStream_t stream) {
  const float* s0   = (const float*)d_in[0];
  const float* s1   = (const float*)d_in[1];
  const float* s2   = (const float*)d_in[2];
  const float* data = (const float*)d_in[3];
  const float* W0   = (const float*)d_in[4];
  const float* b0   = (const float*)d_in[5];
  const float* W1   = (const float*)d_in[6];
  const float* b1   = (const float*)d_in[7];
  const float* W2   = (const float*)d_in[8];
  const float* b2   = (const float*)d_in[9];

  // fp32 masters live directly in d_out: [s0 | s1 | s2].
  float* s0f = (float*)d_out;
  float* s1f = s0f + 2048ull * 1024;
  float* s2f = s1f + 2048ull * 2048;

  char* ws = (char*)d_ws;
  size_t off = 0;
  auto alloc = [&](size_t bytes) -> char* {
    char* p = ws + off; off += (bytes + 255) & ~(size_t)255; return p;
  };
  uint16_t* W0b    = (uint16_t*)alloc(1024ull * 2048 * 2);
  uint16_t* W0Tb   = (uint16_t*)alloc(2048ull * 1024 * 2);
  uint16_t* W1b    = (uint16_t*)alloc(2048ull * 2048 * 2);
  uint16_t* W1Tb   = (uint16_t*)alloc(2048ull * 2048 * 2);
  float*    c2f    = (float*)   alloc(2048ull * 2048 * 4);
  uint16_t* s0b[2] = { (uint16_t*)alloc(2048ull * 1024 * 2),
                       (uint16_t*)alloc(2048ull * 1024 * 2) };
  uint16_t* s1b[2] = { (uint16_t*)alloc(2048ull * 2048 * 2),
                       (uint16_t*)alloc(2048ull * 2048 * 2) };
  uint16_t* s2b[2] = { (uint16_t*)alloc(2048ull * 2048 * 2),
                       (uint16_t*)alloc(2048ull * 2048 * 2) };
  (void)ws_size; (void)in_sizes; (void)n_in; (void)out_size;

  // --- one-time weight prep (fp32 -> bf16) ---
  conv_k<<<1024 * 2048 / 1024, 256, 0, stream>>>(W0, W0b);
  conv_k<<<2048 * 2048 / 1024, 256, 0, stream>>>(W1, W1b);
  dim3 tb(32, 32);
  convT_k<<<dim3(64, 32), tb, 0, stream>>>(W0, W0Tb, 2048, 1024);
  convT_k<<<dim3(64, 64), tb, 0, stream>>>(W1, W1Tb, 2048, 2048);
  // data, W2 -> bf16 into step-"next" shadow buffers (fully overwritten by step 0
  // epilogue before step 1 reads them — safe temps).
  conv_k<<<2048 * 2048 / 1024, 256, 0, stream>>>(data, s1b[1]);
  conv_k<<<2048 * 2048 / 1024, 256, 0, stream>>>(W2, s2b[1]);
  c2_kernel<<<256, 256, 0, stream>>>(s1b[1], s2b[1], b2, c2f);

  // --- state init: fp32 masters (in d_out) + bf16 shadows ---
  init_state<<<2048 * 1024 / 1024, 256, 0, stream>>>(s0, s0f, s0b[0]);
  init_state<<<2048 * 2048 / 1024, 256, 0, stream>>>(s1, s1f, s1b[0]);
  init_state<<<2048 * 2048 / 1024, 256, 0, stream>>>(s2, s2f, s2b[0]);

  // --- 30 Jacobi relaxation steps, double-buffered bf16 shadows ---
  for (int it = 0; it < 30; ++it) {
    const int c = it & 1, n = c ^ 1;
    step_kernel<<<640, 256, 0, stream>>>(
        s0b[c], s1b[c], s2b[c], s0b[n], s1b[n], s2b[n],
        W0b, W0Tb, W1b, W1Tb, b0, b1, c2f, s0f, s1f, s2f);
  }
  // masters already in d_out — no output kernel needed.
}

// Round 8
// 6370.143 us; speedup vs baseline: 1.0084x; 1.0084x over previous
//
#include <hip/hip_runtime.h>
#include <stdint.h>

#define BM 128
#define BN 128
#define BK 64

// s_waitcnt simm16 (gfx9/CDNA): vm[3:0] | exp[6:4]<<4 | lgkm[11:8]<<8 | vm_hi[5:4]<<14
#define WAIT_LGKM0 0xC07F   // lgkmcnt(0), vmcnt/expcnt = no-wait

typedef __bf16 bf16x8 __attribute__((ext_vector_type(8)));
typedef float f32x4 __attribute__((ext_vector_type(4)));

__device__ __forceinline__ float bf2f(uint16_t u) {
  union { uint32_t u32; float f; } x; x.u32 = ((uint32_t)u) << 16; return x.f;
}
// round-to-nearest-even f32 -> bf16 (finite values only)
__device__ __forceinline__ uint16_t f2bf(float f) {
  uint32_t x = __float_as_uint(f);
  uint32_t r = (x + 0x7FFFu + ((x >> 16) & 1u)) >> 16;
  return (uint16_t)r;
}

// --- pipeline helpers -------------------------------------------------------
__device__ __forceinline__ void stage_regs(const uint16_t* ga, const uint16_t* gb,
                                           int ldA, int ldB,
                                           uint4 a[4], uint4 b[4]) {
#pragma unroll
  for (int c = 0; c < 4; ++c) {
    a[c] = *(const uint4*)(ga + (size_t)(c * 32) * ldA);
    b[c] = *(const uint4*)(gb + (size_t)(c * 32) * ldB);
  }
}
__device__ __forceinline__ void write_lds(uint16_t* la, uint16_t* lb,
                                          const uint4 a[4], const uint4 b[4]) {
#pragma unroll
  for (int c = 0; c < 4; ++c) {
    *(uint4*)(la + c * 2048) = a[c];
    *(uint4*)(lb + c * 2048) = b[c];
  }
}
__device__ __forceinline__ void mfma_phase(const uint16_t* ldsA, const uint16_t* ldsB,
                                           int ln, int wr, int wc, f32x4 acc[4][4]) {
#pragma unroll
  for (int kk = 0; kk < 2; ++kk) {
    const int kc = (kk << 2) + (ln >> 4);   // logical 16B chunk in K
    const int sw = (kc ^ (ln & 7)) << 3;    // XOR-swizzled elem offset
    bf16x8 af[4], bfr[4];
#pragma unroll
    for (int mt = 0; mt < 4; ++mt)
      af[mt] = *(const bf16x8*)&ldsA[((wr << 6) + (mt << 4) + (ln & 15)) * BK + sw];
#pragma unroll
    for (int nt = 0; nt < 4; ++nt)
      bfr[nt] = *(const bf16x8*)&ldsB[((wc << 6) + (nt << 4) + (ln & 15)) * BK + sw];
#pragma unroll
    for (int mt = 0; mt < 4; ++mt)
#pragma unroll
      for (int nt = 0; nt < 4; ++nt)
        acc[mt][nt] = __builtin_amdgcn_mfma_f32_16x16x32_bf16(
            af[mt], bfr[nt], acc[mt][nt], 0, 0, 0);
  }
}

// C(BMxBN at m0,n0) += A(MxK row-major bf16) * Bt(NxK row-major bf16)^T
// REGISTER-PIPELINED K-loop, single 32 KB LDS buffer pair:
//   barrier(readers done) -> ds_write tile k (compiler's auto vmcnt wait for
//   these regs lands HERE — one full compute phase after issue) -> issue
//   global_load tile k+1 -> regs -> waitcnt lgkm(0) -> barrier -> compute k.
// Round 7 ran this exact loop but the compiler held VGPR_Count=64 and
// SPILLED the 64 staging VGPRs to scratch (WRITE_SIZE 65->370 MB/step).
// __launch_bounds__(256,2) raises the cap to 256 VGPR/wave -> no spill.
// XOR swizzle: bank-conflict-free frag reads. K-order/MFMA order unchanged
// -> bit-identical numerics (absmax must stay 0.01953125).
__device__ __forceinline__ void gemm_tile(
    const uint16_t* __restrict__ A, int ldA,
    const uint16_t* __restrict__ Bt, int ldB,
    int m0, int n0, int K,
    uint16_t* ldsA, uint16_t* ldsB, f32x4 acc[4][4])
{
  const int t  = threadIdx.x;
  const int ln = t & 63;
  const int wv = t >> 6;
  const int wr = wv >> 1, wc = wv & 1;

  const int row = t >> 3;
  const int gc  = (t & 7) ^ (row & 7);
  const uint16_t* ga = A  + (size_t)(m0 + row) * ldA + (gc << 3);
  const uint16_t* gb = Bt + (size_t)(n0 + row) * ldB + (gc << 3);
  uint16_t* la = ldsA + (t << 3);
  uint16_t* lb = ldsB + (t << 3);

  const int nIter = K >> 6;        // 16 or 32 (always even)
  uint4 ra[4], rb[4], pa[4], pb[4];

  stage_regs(ga, gb, ldA, ldB, ra, rb);  ga += BK; gb += BK;

  for (int kp = 0; kp < (nIter >> 1); ++kp) {
    const int kt = kp << 1;
    // ---- even iter: consume ra/rb, prefetch pa/pb (always valid: kt+1<nIter)
    __builtin_amdgcn_s_barrier();                   // readers of prev tile done
    write_lds(la, lb, ra, rb);                      // auto vmcnt wait (old loads)
    stage_regs(ga, gb, ldA, ldB, pa, pb);  ga += BK; gb += BK;
    __builtin_amdgcn_s_waitcnt(WAIT_LGKM0);         // my ds_writes done
    __builtin_amdgcn_s_barrier();                   // tile visible to all waves
    mfma_phase(ldsA, ldsB, ln, wr, wc, acc);
    // ---- odd iter: consume pa/pb, prefetch ra/rb if a next pair exists
    __builtin_amdgcn_s_barrier();
    write_lds(la, lb, pa, pb);
    if (kt + 2 < nIter) { stage_regs(ga, gb, ldA, ldB, ra, rb); ga += BK; gb += BK; }
    __builtin_amdgcn_s_waitcnt(WAIT_LGKM0);
    __builtin_amdgcn_s_barrier();
    mfma_phase(ldsA, ldsB, ln, wr, wc, acc);
  }
}

// One Jacobi relaxation step, 3 GEMMs fused in one 640-block grid.
// LPT order (long blocks first) + XCD-aware map: XCD x owns bm in {2x,2x+1}.
//  b <256 (mode 1): pre1 = s2 @ W1^T + s0 @ W0   (K=2048 pass + K=1024 pass)
//  b <512 (mode 2): pre2 = s1 @ W1               (Bt = W1Tb)
//  else   (mode 0): pre0 = s1 @ W0^T             (Bt = W0b native)
// fp32 masters (in d_out) updated in place; bf16 shadows double-buffered.
// launch_bounds(256,2): 2 waves/EU min -> 256 VGPR cap -> staging regs don't
// spill (round-7 failure); 2 blocks/CU, same occupancy regime as rounds 4-6.
__global__ void __launch_bounds__(256, 2) step_kernel(
    const uint16_t* __restrict__ s0b_c, const uint16_t* __restrict__ s1b_c,
    const uint16_t* __restrict__ s2b_c,
    uint16_t* __restrict__ s0b_n, uint16_t* __restrict__ s1b_n,
    uint16_t* __restrict__ s2b_n,
    const uint16_t* __restrict__ W0b, const uint16_t* __restrict__ W0Tb,
    const uint16_t* __restrict__ W1b, const uint16_t* __restrict__ W1Tb,
    const float* __restrict__ b0, const float* __restrict__ b1,
    const float* __restrict__ c2f,
    float* __restrict__ s0f, float* __restrict__ s1f, float* __restrict__ s2f)
{
  __shared__ uint16_t ldsA[BM * BK];
  __shared__ uint16_t ldsB[BN * BK];

  f32x4 acc[4][4];
  const f32x4 z = {0.f, 0.f, 0.f, 0.f};
#pragma unroll
  for (int i = 0; i < 4; ++i)
#pragma unroll
    for (int j = 0; j < 4; ++j) acc[i][j] = z;

  const int b = blockIdx.x;
  int mode, bm, bn;
  if (b < 256) {
    mode = 1; const int x = b & 7, j = b >> 3;           // j in [0,32)
    bm = (x << 1) + (j >> 4); bn = j & 15;
    gemm_tile(s2b_c, 2048, W1b, 2048, bm * BM, bn * BN, 2048, ldsA, ldsB, acc);
    gemm_tile(s0b_c, 1024, W0Tb, 1024, bm * BM, bn * BN, 1024, ldsA, ldsB, acc);
  } else if (b < 512) {
    mode = 2; const int u = b - 256, x = u & 7, j = u >> 3;
    bm = (x << 1) + (j >> 4); bn = j & 15;
    gemm_tile(s1b_c, 2048, W1Tb, 2048, bm * BM, bn * BN, 2048, ldsA, ldsB, acc);
  } else {
    mode = 0; const int u = b - 512, x = u & 7, j = u >> 3; // j in [0,16)
    bm = (x << 1) + (j >> 3); bn = j & 7;
    gemm_tile(s1b_c, 2048, W0b, 2048, bm * BM, bn * BN, 2048, ldsA, ldsB, acc);
  }

  const int t = threadIdx.x, wv = t >> 6, ln = t & 63;
  const int wr = wv >> 1, wc = wv & 1;
  const int rb = (ln >> 4) << 2, cc = ln & 15;
  const int m0 = bm * BM, n0 = bn * BN;

#pragma unroll
  for (int mt = 0; mt < 4; ++mt) {
#pragma unroll
    for (int nt = 0; nt < 4; ++nt) {
      const int gn = n0 + (wc << 6) + (nt << 4) + cc;
      float add = 0.f;
      if (mode == 0) add = b0[gn];
      else if (mode == 1) add = b1[gn];
#pragma unroll
      for (int r = 0; r < 4; ++r) {
        const int gm = m0 + (wr << 6) + (mt << 4) + rb + r;
        const float pre = acc[mt][nt][r];
        if (mode == 0) {
          const size_t ix = (size_t)gm * 1024 + gn;
          float nv = 0.8f * s0f[ix] + 0.2f * (pre + add);
          nv = fminf(fmaxf(nv, 0.f), 1.f);
          s0f[ix] = nv;
          s0b_n[ix] = f2bf(nv);
        } else if (mode == 1) {
          const size_t ix = (size_t)gm * 2048 + gn;
          float nv = 0.8f * s1f[ix] + 0.2f * (pre + add);
          nv = fminf(fmaxf(nv, 0.f), 1.f);
          s1f[ix] = nv;
          s1b_n[ix] = f2bf(nv);
        } else {
          const size_t ix = (size_t)gm * 2048 + gn;
          float nv = 0.8f * s2f[ix] + 0.2f * (pre + c2f[ix]);
          nv = fminf(fmaxf(nv, 0.f), 1.f);
          s2f[ix] = nv;
          s2b_n[ix] = f2bf(nv);
        }
      }
    }
  }
}

// c2 = data @ W2^T + b2 (step-invariant), fp32 result.
__global__ void __launch_bounds__(256, 2) c2_kernel(
    const uint16_t* __restrict__ datab,
    const uint16_t* __restrict__ W2b,
    const float* __restrict__ b2,
    float* __restrict__ c2f)
{
  __shared__ uint16_t ldsA[BM * BK];
  __shared__ uint16_t ldsB[BN * BK];
  f32x4 acc[4][4];
  const f32x4 z = {0.f, 0.f, 0.f, 0.f};
#pragma unroll
  for (int i = 0; i < 4; ++i)
#pragma unroll
    for (int j = 0; j < 4; ++j) acc[i][j] = z;

  const int bm = blockIdx.x >> 4, bn = blockIdx.x & 15;
  gemm_tile(datab, 2048, W2b, 2048, bm * BM, bn * BN, 2048, ldsA, ldsB, acc);

  const int t = threadIdx.x, wv = t >> 6, ln = t & 63;
  const int wr = wv >> 1, wc = wv & 1;
  const int rb = (ln >> 4) << 2, cc = ln & 15;
  const int m0 = bm * BM, n0 = bn * BN;
#pragma unroll
  for (int mt = 0; mt < 4; ++mt)
#pragma unroll
    for (int nt = 0; nt < 4; ++nt) {
      const int gn = n0 + (wc << 6) + (nt << 4) + cc;
      const float bb = b2[gn];
#pragma unroll
      for (int r = 0; r < 4; ++r) {
        const int gm = m0 + (wr << 6) + (mt << 4) + rb + r;
        c2f[(size_t)gm * 2048 + gn] = acc[mt][nt][r] + bb;
      }
    }
}

// fp32 -> bf16 straight convert, 4 elems/thread.
__global__ void conv_k(const float* __restrict__ src, uint16_t* __restrict__ dst)
{
  const size_t i4 = ((size_t)blockIdx.x * 256 + threadIdx.x) << 2;
  const float4 v = *(const float4*)(src + i4);
  ushort4 o;
  o.x = f2bf(v.x); o.y = f2bf(v.y); o.z = f2bf(v.z); o.w = f2bf(v.w);
  *(ushort4*)(dst + i4) = o;
}

// fp32 -> bf16 transposed: dst[c*ldD + r] = bf16(src[r*ldS + c]).
__global__ void convT_k(const float* __restrict__ src, uint16_t* __restrict__ dst,
                        int ldS, int ldD)
{
  __shared__ uint16_t tile[32][33];
  const int r0 = blockIdx.y * 32, c0 = blockIdx.x * 32;
  tile[threadIdx.y][threadIdx.x] =
      f2bf(src[(size_t)(r0 + threadIdx.y) * ldS + c0 + threadIdx.x]);
  __syncthreads();
  dst[(size_t)(c0 + threadIdx.y) * ldD + r0 + threadIdx.x] = tile[threadIdx.x][threadIdx.y];
}

// fp32 input -> fp32 master (in d_out) + bf16 shadow. 4 elems/thread.
__global__ void init_state(const float* __restrict__ in,
                           float* __restrict__ sf, uint16_t* __restrict__ sb)
{
  const size_t i4 = ((size_t)blockIdx.x * 256 + threadIdx.x) << 2;
  const float4 v = *(const float4*)(in + i4);
  *(float4*)(sf + i4) = v;
  ushort4 o;
  o.x = f2bf(v.x); o.y = f2bf(v.y); o.z = f2bf(v.z); o.w = f2bf(v.w);
  *(ushort4*)(sb + i4) = o;
}

extern "C" void kernel_launch(void* const* d_in, const int* in_sizes, int n_in,
                              void* d_out, int out_size, void* d_ws, size_t ws_size,
                              hipStream_t stream) {
  const float* s0   = (const float*)d_in[0];
  const float* s1   = (const float*)d_in[1];
  const float* s2   = (const float*)d_in[2];
  const float* data = (const float*)d_in[3];
  const float* W0   = (const float*)d_in[4];
  const float* b0   = (const float*)d_in[5];
  const float* W1   = (const float*)d_in[6];
  const float* b1   = (const float*)d_in[7];
  const float* W2   = (const float*)d_in[8];
  const float* b2   = (const float*)d_in[9];

  // fp32 masters live directly in d_out: [s0 | s1 | s2].
  float* s0f = (float*)d_out;
  float* s1f = s0f + 2048ull * 1024;
  float* s2f = s1f + 2048ull * 2048;

  char* ws = (char*)d_ws;
  size_t off = 0;
  auto alloc = [&](size_t bytes) -> char* {
    char* p = ws + off; off += (bytes + 255) & ~(size_t)255; return p;
  };
  uint16_t* W0b    = (uint16_t*)alloc(1024ull * 2048 * 2);
  uint16_t* W0Tb   = (uint16_t*)alloc(2048ull * 1024 * 2);
  uint16_t* W1b    = (uint16_t*)alloc(2048ull * 2048 * 2);
  uint16_t* W1Tb   = (uint16_t*)alloc(2048ull * 2048 * 2);
  float*    c2f    = (float*)   alloc(2048ull * 2048 * 4);
  uint16_t* s0b[2] = { (uint16_t*)alloc(2048ull * 1024 * 2),
                       (uint16_t*)alloc(2048ull * 1024 * 2) };
  uint16_t* s1b[2] = { (uint16_t*)alloc(2048ull * 2048 * 2),
                       (uint16_t*)alloc(2048ull * 2048 * 2) };
  uint16_t* s2b[2] = { (uint16_t*)alloc(2048ull * 2048 * 2),
                       (uint16_t*)alloc(2048ull * 2048 * 2) };
  (void)ws_size; (void)in_sizes; (void)n_in; (void)out_size;

  // --- one-time weight prep (fp32 -> bf16) ---
  conv_k<<<1024 * 2048 / 1024, 256, 0, stream>>>(W0, W0b);
  conv_k<<<2048 * 2048 / 1024, 256, 0, stream>>>(W1, W1b);
  dim3 tb(32, 32);
  convT_k<<<dim3(64, 32), tb, 0, stream>>>(W0, W0Tb, 2048, 1024);
  convT_k<<<dim3(64, 64), tb, 0, stream>>>(W1, W1Tb, 2048, 2048);
  // data, W2 -> bf16 into step-"next" shadow buffers (fully overwritten by step 0
  // epilogue before step 1 reads them — safe temps).
  conv_k<<<2048 * 2048 / 1024, 256, 0, stream>>>(data, s1b[1]);
  conv_k<<<2048 * 2048 / 1024, 256, 0, stream>>>(W2, s2b[1]);
  c2_kernel<<<256, 256, 0, stream>>>(s1b[1], s2b[1], b2, c2f);

  // --- state init: fp32 masters (in d_out) + bf16 shadows ---
  init_state<<<2048 * 1024 / 1024, 256, 0, stream>>>(s0, s0f, s0b[0]);
  init_state<<<2048 * 2048 / 1024, 256, 0, stream>>>(s1, s1f, s1b[0]);
  init_state<<<2048 * 2048 / 1024, 256, 0, stream>>>(s2, s2f, s2b[0]);

  // --- 30 Jacobi relaxation steps, double-buffered bf16 shadows ---
  for (int it = 0; it < 30; ++it) {
    const int c = it & 1, n = c ^ 1;
    step_kernel<<<640, 256, 0, stream>>>(
        s0b[c], s1b[c], s2b[c], s0b[n], s1b[n], s2b[n],
        W0b, W0Tb, W1b, W1Tb, b0, b1, c2f, s0f, s1f, s2f);
  }
  // masters already in d_out — no output kernel needed.
}

// Round 9
// 3089.376 us; speedup vs baseline: 2.0792x; 2.0620x over previous
//
#include <hip/hip_runtime.h>
#include <stdint.h>

#define BM 128
#define BN 128
#define BK 64

// s_waitcnt simm16 (gfx9/CDNA): vm[3:0] | exp[6:4]<<4 | lgkm[11:8]<<8
#define WAIT_LGKM0 0xC07F   // lgkmcnt(0), vmcnt/expcnt = no-wait

typedef __bf16 bf16x8 __attribute__((ext_vector_type(8)));
typedef float f32x4 __attribute__((ext_vector_type(4)));

__device__ __forceinline__ float bf2f(uint16_t u) {
  union { uint32_t u32; float f; } x; x.u32 = ((uint32_t)u) << 16; return x.f;
}
// round-to-nearest-even f32 -> bf16 (finite values only)
__device__ __forceinline__ uint16_t f2bf(float f) {
  uint32_t x = __float_as_uint(f);
  uint32_t r = (x + 0x7FFFu + ((x >> 16) & 1u)) >> 16;
  return (uint16_t)r;
}

__device__ __forceinline__ void mfma_phase(const uint16_t* ldsA, const uint16_t* ldsB,
                                           int ln, int wr, int wc, f32x4 acc[4][4]) {
#pragma unroll
  for (int kk = 0; kk < 2; ++kk) {
    const int kc = (kk << 2) + (ln >> 4);   // logical 16B chunk in K
    const int sw = (kc ^ (ln & 7)) << 3;    // XOR-swizzled elem offset
    bf16x8 af[4], bfr[4];
#pragma unroll
    for (int mt = 0; mt < 4; ++mt)
      af[mt] = *(const bf16x8*)&ldsA[((wr << 6) + (mt << 4) + (ln & 15)) * BK + sw];
#pragma unroll
    for (int nt = 0; nt < 4; ++nt)
      bfr[nt] = *(const bf16x8*)&ldsB[((wc << 6) + (nt << 4) + (ln & 15)) * BK + sw];
#pragma unroll
    for (int mt = 0; mt < 4; ++mt)
#pragma unroll
      for (int nt = 0; nt < 4; ++nt)
        acc[mt][nt] = __builtin_amdgcn_mfma_f32_16x16x32_bf16(
            af[mt], bfr[nt], acc[mt][nt], 0, 0, 0);
  }
}

// C(BMxBN at m0,n0) += A(MxK row-major bf16) * Bt(NxK row-major bf16)^T
// Register-pipelined K-loop, single 32 KB LDS buffer pair.
// Rounds 7/8 post-mortem: staging lived in uint4 ARRAYS passed through helper
// fn pointers -> SROA failed -> scratch-backed stack (WRITE_SIZE 65->375 MB/step,
// VGPR_Count stuck at 64/72 regardless of launch bounds). This version uses 16
// individually NAMED uint4 registers, loads/stores inline via macros — nothing
// to demote to scratch. Pipeline per K-tile:
//   barrier(readers done) -> ds_write tile k (auto vmcnt wait for its loads
//   lands here, one full compute phase after issue) -> issue global_load tile
//   k+1 into the other named set -> waitcnt lgkm(0) -> barrier -> compute k.
// XOR swizzle: conflict-free frag reads. K/MFMA order unchanged ->
// bit-identical numerics (absmax must stay 0.01953125).
__device__ __forceinline__ void gemm_tile(
    const uint16_t* __restrict__ A, int ldA,
    const uint16_t* __restrict__ Bt, int ldB,
    int m0, int n0, int K,
    uint16_t* ldsA, uint16_t* ldsB, f32x4 acc[4][4])
{
  const int t  = threadIdx.x;
  const int ln = t & 63;
  const int wv = t >> 6;
  const int wr = wv >> 1, wc = wv & 1;

  const int row = t >> 3;
  const int gc  = (t & 7) ^ (row & 7);
  const uint16_t* ga = A  + (size_t)(m0 + row) * ldA + (gc << 3);
  const uint16_t* gb = Bt + (size_t)(n0 + row) * ldB + (gc << 3);
  uint16_t* la = ldsA + (t << 3);
  uint16_t* lb = ldsB + (t << 3);

  const size_t sA = (size_t)32 * ldA;
  const size_t sB = (size_t)32 * ldB;
  const int nIter = K >> 6;            // 16 or 32 (always even)

  uint4 ea0, ea1, ea2, ea3, eb0, eb1, eb2, eb3;  // even-tile staging regs
  uint4 oa0, oa1, oa2, oa3, ob0, ob1, ob2, ob3;  // odd-tile staging regs

#define LOADSET(x0,x1,x2,x3,y0,y1,y2,y3)          \
  x0 = *(const uint4*)(ga);                       \
  x1 = *(const uint4*)(ga + sA);                  \
  x2 = *(const uint4*)(ga + 2 * sA);              \
  x3 = *(const uint4*)(ga + 3 * sA);              \
  y0 = *(const uint4*)(gb);                       \
  y1 = *(const uint4*)(gb + sB);                  \
  y2 = *(const uint4*)(gb + 2 * sB);              \
  y3 = *(const uint4*)(gb + 3 * sB);              \
  ga += BK; gb += BK;

#define STORESET(x0,x1,x2,x3,y0,y1,y2,y3)         \
  *(uint4*)(la)        = x0;                      \
  *(uint4*)(la + 2048) = x1;                      \
  *(uint4*)(la + 4096) = x2;                      \
  *(uint4*)(la + 6144) = x3;                      \
  *(uint4*)(lb)        = y0;                      \
  *(uint4*)(lb + 2048) = y1;                      \
  *(uint4*)(lb + 4096) = y2;                      \
  *(uint4*)(lb + 6144) = y3;

  LOADSET(ea0, ea1, ea2, ea3, eb0, eb1, eb2, eb3)          // tile 0

  for (int kp = 0; kp < (nIter >> 1); ++kp) {
    // ---- even tile: consume e-set, prefetch o-set (kt+1 < nIter always)
    __builtin_amdgcn_s_barrier();                          // readers of prev tile done
    STORESET(ea0, ea1, ea2, ea3, eb0, eb1, eb2, eb3)       // auto vmcnt wait here
    LOADSET(oa0, oa1, oa2, oa3, ob0, ob1, ob2, ob3)
    __builtin_amdgcn_s_waitcnt(WAIT_LGKM0);                // my ds_writes done
    __builtin_amdgcn_s_barrier();                          // tile visible
    mfma_phase(ldsA, ldsB, ln, wr, wc, acc);
    // ---- odd tile: consume o-set, prefetch e-set if another pair exists
    __builtin_amdgcn_s_barrier();
    STORESET(oa0, oa1, oa2, oa3, ob0, ob1, ob2, ob3)
    if (kp + 1 < (nIter >> 1)) {
      LOADSET(ea0, ea1, ea2, ea3, eb0, eb1, eb2, eb3)
    }
    __builtin_amdgcn_s_waitcnt(WAIT_LGKM0);
    __builtin_amdgcn_s_barrier();
    mfma_phase(ldsA, ldsB, ln, wr, wc, acc);
  }
#undef LOADSET
#undef STORESET
}

// One Jacobi relaxation step, 3 GEMMs fused in one 640-block grid.
// LPT order (long blocks first) + XCD-aware map: XCD x owns bm in {2x,2x+1}.
//  b <256 (mode 1): pre1 = s2 @ W1^T + s0 @ W0   (K=2048 pass + K=1024 pass)
//  b <512 (mode 2): pre2 = s1 @ W1               (Bt = W1Tb)
//  else   (mode 0): pre0 = s1 @ W0^T             (Bt = W0b native)
// fp32 masters (in d_out) updated in place; bf16 shadows double-buffered.
__global__ void __launch_bounds__(256, 2) step_kernel(
    const uint16_t* __restrict__ s0b_c, const uint16_t* __restrict__ s1b_c,
    const uint16_t* __restrict__ s2b_c,
    uint16_t* __restrict__ s0b_n, uint16_t* __restrict__ s1b_n,
    uint16_t* __restrict__ s2b_n,
    const uint16_t* __restrict__ W0b, const uint16_t* __restrict__ W0Tb,
    const uint16_t* __restrict__ W1b, const uint16_t* __restrict__ W1Tb,
    const float* __restrict__ b0, const float* __restrict__ b1,
    const float* __restrict__ c2f,
    float* __restrict__ s0f, float* __restrict__ s1f, float* __restrict__ s2f)
{
  __shared__ uint16_t ldsA[BM * BK];
  __shared__ uint16_t ldsB[BN * BK];

  f32x4 acc[4][4];
  const f32x4 z = {0.f, 0.f, 0.f, 0.f};
#pragma unroll
  for (int i = 0; i < 4; ++i)
#pragma unroll
    for (int j = 0; j < 4; ++j) acc[i][j] = z;

  const int b = blockIdx.x;
  int mode, bm, bn;
  if (b < 256) {
    mode = 1; const int x = b & 7, j = b >> 3;           // j in [0,32)
    bm = (x << 1) + (j >> 4); bn = j & 15;
    gemm_tile(s2b_c, 2048, W1b, 2048, bm * BM, bn * BN, 2048, ldsA, ldsB, acc);
    gemm_tile(s0b_c, 1024, W0Tb, 1024, bm * BM, bn * BN, 1024, ldsA, ldsB, acc);
  } else if (b < 512) {
    mode = 2; const int u = b - 256, x = u & 7, j = u >> 3;
    bm = (x << 1) + (j >> 4); bn = j & 15;
    gemm_tile(s1b_c, 2048, W1Tb, 2048, bm * BM, bn * BN, 2048, ldsA, ldsB, acc);
  } else {
    mode = 0; const int u = b - 512, x = u & 7, j = u >> 3; // j in [0,16)
    bm = (x << 1) + (j >> 3); bn = j & 7;
    gemm_tile(s1b_c, 2048, W0b, 2048, bm * BM, bn * BN, 2048, ldsA, ldsB, acc);
  }

  const int t = threadIdx.x, wv = t >> 6, ln = t & 63;
  const int wr = wv >> 1, wc = wv & 1;
  const int rb = (ln >> 4) << 2, cc = ln & 15;
  const int m0 = bm * BM, n0 = bn * BN;

#pragma unroll
  for (int mt = 0; mt < 4; ++mt) {
#pragma unroll
    for (int nt = 0; nt < 4; ++nt) {
      const int gn = n0 + (wc << 6) + (nt << 4) + cc;
      float add = 0.f;
      if (mode == 0) add = b0[gn];
      else if (mode == 1) add = b1[gn];
#pragma unroll
      for (int r = 0; r < 4; ++r) {
        const int gm = m0 + (wr << 6) + (mt << 4) + rb + r;
        const float pre = acc[mt][nt][r];
        if (mode == 0) {
          const size_t ix = (size_t)gm * 1024 + gn;
          float nv = 0.8f * s0f[ix] + 0.2f * (pre + add);
          nv = fminf(fmaxf(nv, 0.f), 1.f);
          s0f[ix] = nv;
          s0b_n[ix] = f2bf(nv);
        } else if (mode == 1) {
          const size_t ix = (size_t)gm * 2048 + gn;
          float nv = 0.8f * s1f[ix] + 0.2f * (pre + add);
          nv = fminf(fmaxf(nv, 0.f), 1.f);
          s1f[ix] = nv;
          s1b_n[ix] = f2bf(nv);
        } else {
          const size_t ix = (size_t)gm * 2048 + gn;
          float nv = 0.8f * s2f[ix] + 0.2f * (pre + c2f[ix]);
          nv = fminf(fmaxf(nv, 0.f), 1.f);
          s2f[ix] = nv;
          s2b_n[ix] = f2bf(nv);
        }
      }
    }
  }
}

// c2 = data @ W2^T + b2 (step-invariant), fp32 result.
__global__ void __launch_bounds__(256, 2) c2_kernel(
    const uint16_t* __restrict__ datab,
    const uint16_t* __restrict__ W2b,
    const float* __restrict__ b2,
    float* __restrict__ c2f)
{
  __shared__ uint16_t ldsA[BM * BK];
  __shared__ uint16_t ldsB[BN * BK];
  f32x4 acc[4][4];
  const f32x4 z = {0.f, 0.f, 0.f, 0.f};
#pragma unroll
  for (int i = 0; i < 4; ++i)
#pragma unroll
    for (int j = 0; j < 4; ++j) acc[i][j] = z;

  const int bm = blockIdx.x >> 4, bn = blockIdx.x & 15;
  gemm_tile(datab, 2048, W2b, 2048, bm * BM, bn * BN, 2048, ldsA, ldsB, acc);

  const int t = threadIdx.x, wv = t >> 6, ln = t & 63;
  const int wr = wv >> 1, wc = wv & 1;
  const int rb = (ln >> 4) << 2, cc = ln & 15;
  const int m0 = bm * BM, n0 = bn * BN;
#pragma unroll
  for (int mt = 0; mt < 4; ++mt)
#pragma unroll
    for (int nt = 0; nt < 4; ++nt) {
      const int gn = n0 + (wc << 6) + (nt << 4) + cc;
      const float bb = b2[gn];
#pragma unroll
      for (int r = 0; r < 4; ++r) {
        const int gm = m0 + (wr << 6) + (mt << 4) + rb + r;
        c2f[(size_t)gm * 2048 + gn] = acc[mt][nt][r] + bb;
      }
    }
}

// fp32 -> bf16 straight convert, 4 elems/thread.
__global__ void conv_k(const float* __restrict__ src, uint16_t* __restrict__ dst)
{
  const size_t i4 = ((size_t)blockIdx.x * 256 + threadIdx.x) << 2;
  const float4 v = *(const float4*)(src + i4);
  ushort4 o;
  o.x = f2bf(v.x); o.y = f2bf(v.y); o.z = f2bf(v.z); o.w = f2bf(v.w);
  *(ushort4*)(dst + i4) = o;
}

// fp32 -> bf16 transposed: dst[c*ldD + r] = bf16(src[r*ldS + c]).
__global__ void convT_k(const float* __restrict__ src, uint16_t* __restrict__ dst,
                        int ldS, int ldD)
{
  __shared__ uint16_t tile[32][33];
  const int r0 = blockIdx.y * 32, c0 = blockIdx.x * 32;
  tile[threadIdx.y][threadIdx.x] =
      f2bf(src[(size_t)(r0 + threadIdx.y) * ldS + c0 + threadIdx.x]);
  __syncthreads();
  dst[(size_t)(c0 + threadIdx.y) * ldD + r0 + threadIdx.x] = tile[threadIdx.x][threadIdx.y];
}

// fp32 input -> fp32 master (in d_out) + bf16 shadow. 4 elems/thread.
__global__ void init_state(const float* __restrict__ in,
                           float* __restrict__ sf, uint16_t* __restrict__ sb)
{
  const size_t i4 = ((size_t)blockIdx.x * 256 + threadIdx.x) << 2;
  const float4 v = *(const float4*)(in + i4);
  *(float4*)(sf + i4) = v;
  ushort4 o;
  o.x = f2bf(v.x); o.y = f2bf(v.y); o.z = f2bf(v.z); o.w = f2bf(v.w);
  *(ushort4*)(sb + i4) = o;
}

extern "C" void kernel_launch(void* const* d_in, const int* in_sizes, int n_in,
                              void* d_out, int out_size, void* d_ws, size_t ws_size,
                              hipStream_t stream) {
  const float* s0   = (const float*)d_in[0];
  const float* s1   = (const float*)d_in[1];
  const float* s2   = (const float*)d_in[2];
  const float* data = (const float*)d_in[3];
  const float* W0   = (const float*)d_in[4];
  const float* b0   = (const float*)d_in[5];
  const float* W1   = (const float*)d_in[6];
  const float* b1   = (const float*)d_in[7];
  const float* W2   = (const float*)d_in[8];
  const float* b2   = (const float*)d_in[9];

  // fp32 masters live directly in d_out: [s0 | s1 | s2].
  float* s0f = (float*)d_out;
  float* s1f = s0f + 2048ull * 1024;
  float* s2f = s1f + 2048ull * 2048;

  char* ws = (char*)d_ws;
  size_t off = 0;
  auto alloc = [&](size_t bytes) -> char* {
    char* p = ws + off; off += (bytes + 255) & ~(size_t)255; return p;
  };
  uint16_t* W0b    = (uint16_t*)alloc(1024ull * 2048 * 2);
  uint16_t* W0Tb   = (uint16_t*)alloc(2048ull * 1024 * 2);
  uint16_t* W1b    = (uint16_t*)alloc(2048ull * 2048 * 2);
  uint16_t* W1Tb   = (uint16_t*)alloc(2048ull * 2048 * 2);
  float*    c2f    = (float*)   alloc(2048ull * 2048 * 4);
  uint16_t* s0b[2] = { (uint16_t*)alloc(2048ull * 1024 * 2),
                       (uint16_t*)alloc(2048ull * 1024 * 2) };
  uint16_t* s1b[2] = { (uint16_t*)alloc(2048ull * 2048 * 2),
                       (uint16_t*)alloc(2048ull * 2048 * 2) };
  uint16_t* s2b[2] = { (uint16_t*)alloc(2048ull * 2048 * 2),
                       (uint16_t*)alloc(2048ull * 2048 * 2) };
  (void)ws_size; (void)in_sizes; (void)n_in; (void)out_size;

  // --- one-time weight prep (fp32 -> bf16) ---
  conv_k<<<1024 * 2048 / 1024, 256, 0, stream>>>(W0, W0b);
  conv_k<<<2048 * 2048 / 1024, 256, 0, stream>>>(W1, W1b);
  dim3 tb(32, 32);
  convT_k<<<dim3(64, 32), tb, 0, stream>>>(W0, W0Tb, 2048, 1024);
  convT_k<<<dim3(64, 64), tb, 0, stream>>>(W1, W1Tb, 2048, 2048);
  // data, W2 -> bf16 into step-"next" shadow buffers (fully overwritten by step 0
  // epilogue before step 1 reads them — safe temps).
  conv_k<<<2048 * 2048 / 1024, 256, 0, stream>>>(data, s1b[1]);
  conv_k<<<2048 * 2048 / 1024, 256, 0, stream>>>(W2, s2b[1]);
  c2_kernel<<<256, 256, 0, stream>>>(s1b[1], s2b[1], b2, c2f);

  // --- state init: fp32 masters (in d_out) + bf16 shadows ---
  init_state<<<2048 * 1024 / 1024, 256, 0, stream>>>(s0, s0f, s0b[0]);
  init_state<<<2048 * 2048 / 1024, 256, 0, stream>>>(s1, s1f, s1b[0]);
  init_state<<<2048 * 2048 / 1024, 256, 0, stream>>>(s2, s2f, s2b[0]);

  // --- 30 Jacobi relaxation steps, double-buffered bf16 shadows ---
  for (int it = 0; it < 30; ++it) {
    const int c = it & 1, n = c ^ 1;
    step_kernel<<<640, 256, 0, stream>>>(
        s0b[c], s1b[c], s2b[c], s0b[n], s1b[n], s2b[n],
        W0b, W0Tb, W1b, W1Tb, b0, b1, c2f, s0f, s1f, s2f);
  }
  // masters already in d_out — no output kernel needed.
}